// Round 6
// baseline (34.355 us; speedup 1.0000x reference)
//
#include <hip/hip_runtime.h>
#include <math.h>

#define B_TOTAL 16384
#define RR 64
#define KK 256          // 4*R
#define MM 512
#define ROWS 32         // batch rows per gemm block
#define NCH 8           // K chunks of 32
#define MI 2            // 16-row M-tiles per wave
#define INV2PI 0.15915494309189535f

typedef __attribute__((ext_vector_type(8))) short short8;
typedef __attribute__((ext_vector_type(4))) float floatx4;

static __device__ inline ushort f2bf(float x) {
    union { float f; unsigned u; } v; v.f = x;
    unsigned r = v.u + 0x7FFFu + ((v.u >> 16) & 1u);   // RNE
    return (ushort)(r >> 16);
}
static __device__ inline float bf2f(ushort h) {
    union { float f; unsigned u; } v; v.u = ((unsigned)h) << 16;
    return v.f;
}

// DPP mov with multiplicative identity for invalid/unwritten lanes
template<int CTRL, int RMASK>
static __device__ inline float dpp_mov1(float src) {
    int s = __builtin_bit_cast(int, src);
    int o = __builtin_bit_cast(int, 1.0f);
    int r = __builtin_amdgcn_update_dpp(o, s, CTRL, RMASK, 0xF, false);
    return __builtin_bit_cast(float, r);
}
template<int CTRL>
static __device__ inline float dpp_swap(float src) {
    int s = __builtin_bit_cast(int, src);
    int r = __builtin_amdgcn_update_dpp(s, s, CTRL, 0xF, 0xF, false);
    return __builtin_bit_cast(float, r);
}
static __device__ inline float red16(float x) {
    x += dpp_swap<0xB1>(x);    // quad_perm xor1
    x += dpp_swap<0x4E>(x);    // quad_perm xor2
    x += dpp_swap<0x141>(x);   // row_half_mirror
    x += dpp_swap<0x140>(x);   // row_mirror
    return x;
}

// ---- kernel 1: prep.  Blocks 0..31: S/(2pi) -> Bhi/Blo (frag order).
//                 Blocks 32..543: stick-breaking -> Ahi/Alo (frag order). ----
__global__ __launch_bounds__(512, 4)
void prep(const float* __restrict__ S, const int* __restrict__ indices,
          const float* __restrict__ v0, const float* __restrict__ v1,
          const float* __restrict__ v2, const float* __restrict__ v3,
          ushort* __restrict__ Bhi, ushort* __restrict__ Blo,
          ushort* __restrict__ Ahi, ushort* __restrict__ Alo)
{
    const int bid = blockIdx.x;
    const int tid = threadIdx.x;

    if (bid < 32) {
        // --- S conversion: F = o*512 + c, 8 elems each ---
        const int F = bid * 512 + tid;
        const int o = F >> 9;
        const int c = F & 511;
        const float* src = &S[c * KK + o * 8];
        float v[8];
        *reinterpret_cast<float4*>(&v[0]) = *reinterpret_cast<const float4*>(src);
        *reinterpret_cast<float4*>(&v[4]) = *reinterpret_cast<const float4*>(src + 4);
        short8 hv, lv;
        #pragma unroll
        for (int j = 0; j < 8; ++j) {
            const float sv = v[j] * INV2PI;
            const ushort h = f2bf(sv);
            hv[j] = (short)h;
            lv[j] = (short)f2bf(sv - bf2f(h));
        }
        *reinterpret_cast<short8*>(&Bhi[F * 8]) = hv;
        *reinterpret_cast<short8*>(&Blo[F * 8]) = lv;
        return;
    }

    // --- embedding: each wave handles 16 (row,mod) pairs ---
    const int ebid = bid - 32;
    const int wid  = __builtin_amdgcn_readfirstlane(tid >> 6);
    const int lane = tid & 63;
    const int gw   = ebid * 8 + wid;           // 0..4095
    const int* ip  = indices + gw * 16;        // uniform -> s_load

    const float* vts[4] = {v0, v1, v2, v3};
    float vh[16];
    #pragma unroll
    for (int it = 0; it < 16; ++it) {
        const int mod = it & 3;                // gw*16 ≡ 0 (mod 4)
        vh[it] = vts[mod][ip[it] * RR + lane];
    }

    // lane -> element coords within A fragment layout
    const int k_lo = lane & 31;                // k%32 per half
    const int lg   = (lane >> 3) & 3;
    const int e    = lane & 7;
    const int chp  = lane >> 5;                // 0/1: which 32-chunk of the mod

    #pragma unroll
    for (int it = 0; it < 16; ++it) {
        const int p   = gw * 16 + it;
        const int row = p >> 2;
        const int mod = p & 3;

        const float t  = __expf(vh[it]);                    // e^{vh}
        const float um = __builtin_amdgcn_rcpf(1.f + t);    // sigmoid(-vh)
        float pr = um;                                      // inclusive scan
        pr *= dpp_mov1<0x111, 0xF>(pr);   // row_shr:1
        pr *= dpp_mov1<0x112, 0xF>(pr);   // row_shr:2
        pr *= dpp_mov1<0x114, 0xF>(pr);   // row_shr:4
        pr *= dpp_mov1<0x118, 0xF>(pr);   // row_shr:8
        pr *= dpp_mov1<0x142, 0xA>(pr);   // row_bcast:15
        pr *= dpp_mov1<0x143, 0xC>(pr);   // row_bcast:31
        const float x = t * pr;           // sigmoid(vh) * exclusive-prod

        const ushort h = f2bf(x);
        const ushort l = f2bf(x - bf2f(h));

        const int ch   = mod * 2 + chp;
        const int uidx = ((((row >> 4) * NCH + ch) * 4 + lg) * 16 + (row & 15)) * 8 + e;
        Ahi[uidx] = h;
        Alo[uidx] = l;
    }
}

// ---- kernel 2: pure streaming MFMA GEMM + sincos + reduce (no operand LDS) ----
__global__ __launch_bounds__(512, 4)
void gemm(const ushort* __restrict__ Bhi, const ushort* __restrict__ Blo,
          const ushort* __restrict__ Ahi, const ushort* __restrict__ Alo,
          const float* __restrict__ bvec, const float* __restrict__ w_mu,
          float* __restrict__ out)
{
    __shared__ float red[8][ROWS];

    const int tid = threadIdx.x;
    const int rowBase = blockIdx.x * ROWS;
    const int rb0 = rowBase >> 4;
    const int wid  = __builtin_amdgcn_readfirstlane(tid >> 6);
    const int lane = tid & 63;
    const int l15  = lane & 15;
    const int lg   = lane >> 4;
    const int wcol0 = wid * 64;

    floatx4 acc[MI][4];
    #pragma unroll
    for (int mi = 0; mi < MI; ++mi)
        #pragma unroll
        for (int ni = 0; ni < 4; ++ni)
            acc[mi][ni] = (floatx4){0.f, 0.f, 0.f, 0.f};

    #pragma unroll
    for (int ch = 0; ch < NCH; ++ch) {
        short8 ah[MI], al[MI];
        #pragma unroll
        for (int mi = 0; mi < MI; ++mi) {
            const int ab = ((((rb0 + mi) * NCH + ch) * 4 + lg) * 16 + l15) * 8;
            ah[mi] = *reinterpret_cast<const short8*>(&Ahi[ab]);
            al[mi] = *reinterpret_cast<const short8*>(&Alo[ab]);
        }
        #pragma unroll
        for (int ni = 0; ni < 4; ++ni) {
            const int off = ((ch * 4 + lg) * 512 + wcol0 + ni * 16 + l15) * 8;
            const short8 bh = *reinterpret_cast<const short8*>(&Bhi[off]);
            const short8 bl = *reinterpret_cast<const short8*>(&Blo[off]);
            #pragma unroll
            for (int mi = 0; mi < MI; ++mi) {
                acc[mi][ni] = __builtin_amdgcn_mfma_f32_16x16x32_bf16(ah[mi], bh, acc[mi][ni], 0, 0, 0);
                acc[mi][ni] = __builtin_amdgcn_mfma_f32_16x16x32_bf16(ah[mi], bl, acc[mi][ni], 0, 0, 0);
                acc[mi][ni] = __builtin_amdgcn_mfma_f32_16x16x32_bf16(al[mi], bh, acc[mi][ni], 0, 0, 0);
            }
        }
    }

    // ---- epilogue: +b', hw sincos (revolutions), dot w_mu, reduce ----
    float rp[MI][4];
    #pragma unroll
    for (int mi = 0; mi < MI; ++mi)
        #pragma unroll
        for (int r = 0; r < 4; ++r) rp[mi][r] = 0.f;

    #pragma unroll
    for (int ni = 0; ni < 4; ++ni) {
        const int c = wcol0 + ni * 16 + l15;
        const float bb = bvec[c] * INV2PI;
        const float w1 = w_mu[c];
        const float w2 = w_mu[MM + c];
        #pragma unroll
        for (int mi = 0; mi < MI; ++mi)
            #pragma unroll
            for (int r = 0; r < 4; ++r) {
                const float psi = acc[mi][ni][r] + bb;      // revolutions
                const float sn = __builtin_amdgcn_sinf(psi);
                const float cs = __builtin_amdgcn_cosf(psi);
                rp[mi][r] = fmaf(cs, w1, fmaf(sn, w2, rp[mi][r]));
            }
    }

    #pragma unroll
    for (int mi = 0; mi < MI; ++mi)
        #pragma unroll
        for (int r = 0; r < 4; ++r) {
            const float v = red16(rp[mi][r]);
            if (l15 == 0) red[wid][mi * 16 + lg * 4 + r] = v;
        }
    __syncthreads();

    if (tid < ROWS) {
        float s = 0.f;
        #pragma unroll
        for (int w = 0; w < 8; ++w) s += red[w][tid];
        out[rowBase + tid] = 1.f / (1.f + expf(-s));
    }
}

extern "C" void kernel_launch(void* const* d_in, const int* in_sizes, int n_in,
                              void* d_out, int out_size, void* d_ws, size_t ws_size,
                              hipStream_t stream) {
    const int*   indices = (const int*)d_in[0];
    const float* v0 = (const float*)d_in[1];
    const float* v1 = (const float*)d_in[2];
    const float* v2 = (const float*)d_in[3];
    const float* v3 = (const float*)d_in[4];
    const float* S  = (const float*)d_in[5];
    const float* bb = (const float*)d_in[6];
    const float* w  = (const float*)d_in[7];
    float* out = (float*)d_out;

    ushort* Bhi = (ushort*)d_ws;                 // 512*256 bf16 = 256 KB
    ushort* Blo = Bhi + MM * KK;                 // 256 KB
    ushort* Ahi = Blo + MM * KK;                 // 16384*256 bf16 = 8 MB
    ushort* Alo = Ahi + (size_t)B_TOTAL * KK;    // 8 MB

    hipLaunchKernelGGL(prep, dim3(32 + 512), dim3(512), 0, stream,
                       S, indices, v0, v1, v2, v3, Bhi, Blo, Ahi, Alo);
    hipLaunchKernelGGL(gemm, dim3(B_TOTAL / ROWS), dim3(512), 0, stream,
                       Bhi, Blo, Ahi, Alo, bb, w, out);
}

// Round 7
// 32.088 us; speedup vs baseline: 1.0707x; 1.0707x over previous
//
#include <hip/hip_runtime.h>
#include <math.h>

#define B_TOTAL 16384
#define RR 64
#define KK 256          // 4*R
#define MM 512
#define ROWS 32         // batch rows per block
#define NCH 8           // K chunks of 32
#define MI 2            // 16-row M-tiles per wave
#define ASTR 264        // A LDS row stride (bf16 elems)
#define INV2PI 0.15915494309189535f

typedef __attribute__((ext_vector_type(8))) short short8;
typedef __attribute__((ext_vector_type(4))) float floatx4;

static __device__ inline ushort f2bf(float x) {
    union { float f; unsigned u; } v; v.f = x;
    unsigned r = v.u + 0x7FFFu + ((v.u >> 16) & 1u);   // RNE
    return (ushort)(r >> 16);
}
static __device__ inline float bf2f(ushort h) {
    union { float f; unsigned u; } v; v.u = ((unsigned)h) << 16;
    return v.f;
}

// DPP mov with multiplicative identity for invalid/unwritten lanes
template<int CTRL, int RMASK>
static __device__ inline float dpp_mov1(float src) {
    int s = __builtin_bit_cast(int, src);
    int o = __builtin_bit_cast(int, 1.0f);
    int r = __builtin_amdgcn_update_dpp(o, s, CTRL, RMASK, 0xF, false);
    return __builtin_bit_cast(float, r);
}
template<int CTRL>
static __device__ inline float dpp_swap(float src) {
    int s = __builtin_bit_cast(int, src);
    int r = __builtin_amdgcn_update_dpp(s, s, CTRL, 0xF, 0xF, false);
    return __builtin_bit_cast(float, r);
}
static __device__ inline float red16(float x) {
    x += dpp_swap<0xB1>(x);    // quad_perm xor1
    x += dpp_swap<0x4E>(x);    // quad_perm xor2
    x += dpp_swap<0x141>(x);   // row_half_mirror
    x += dpp_swap<0x140>(x);   // row_mirror
    return x;
}

// ---- kernel 1: S -> hi/lo bf16 of S/(2*pi), MFMA B-fragment order ----
__global__ __launch_bounds__(256)
void conv_S(const float* __restrict__ S, ushort* __restrict__ Bhi,
            ushort* __restrict__ Blo)
{
    const int F = blockIdx.x * 256 + threadIdx.x;   // F = o*512 + c
    const int o = F >> 9;
    const int c = F & 511;
    const float* src = &S[c * KK + o * 8];
    float v[8];
    *reinterpret_cast<float4*>(&v[0]) = *reinterpret_cast<const float4*>(src);
    *reinterpret_cast<float4*>(&v[4]) = *reinterpret_cast<const float4*>(src + 4);
    short8 hv, lv;
    #pragma unroll
    for (int j = 0; j < 8; ++j) {
        const float sv = v[j] * INV2PI;   // pre-scale: sincos in revolutions
        const ushort h = f2bf(sv);
        hv[j] = (short)h;
        lv[j] = (short)f2bf(sv - bf2f(h));
    }
    *reinterpret_cast<short8*>(&Bhi[F * 8]) = hv;
    *reinterpret_cast<short8*>(&Blo[F * 8]) = lv;
}

// ---- kernel 2: gather + stick-break + MFMA + sincos + reduce ----
__global__ __launch_bounds__(512, 6)
void nest2_mfma(const int* __restrict__ indices,
                const float* __restrict__ v0, const float* __restrict__ v1,
                const float* __restrict__ v2, const float* __restrict__ v3,
                const ushort* __restrict__ Bhi, const ushort* __restrict__ Blo,
                const float* __restrict__ bvec, const float* __restrict__ w_mu,
                float* __restrict__ out)
{
    __shared__ alignas(16) ushort Ahi[ROWS * ASTR];
    __shared__ float red[8][ROWS];

    const int tid = threadIdx.x;
    const int rowBase = blockIdx.x * ROWS;
    const int wid  = __builtin_amdgcn_readfirstlane(tid >> 6);
    const int lane = tid & 63;
    const int l15  = lane & 15;
    const int lg   = lane >> 4;
    const int wcol0 = wid * 64;

    // ---- gather loads (wave-uniform row addresses -> coalesced) ----
    const int* ip = indices + rowBase * 4 + wid * 16;
    const float* vts[4] = {v0, v1, v2, v3};
    float vh[16];
    #pragma unroll
    for (int it = 0; it < 16; ++it) {
        const int mod = it & 3;            // wid*16 ≡ 0 (mod 4)
        vh[it] = vts[mod][ip[it] * RR + lane];
    }

    // ---- stick-breaking via DPP product-scan -> Ahi (bf16) ----
    #pragma unroll
    for (int it = 0; it < 16; ++it) {
        const int p   = wid * 16 + it;
        const int row = p >> 2;
        const int mod = p & 3;
        const float t  = __expf(vh[it]);                    // e^{vh}
        const float um = __builtin_amdgcn_rcpf(1.f + t);    // sigmoid(-vh)
        float pr = um;                                      // inclusive scan
        pr *= dpp_mov1<0x111, 0xF>(pr);   // row_shr:1
        pr *= dpp_mov1<0x112, 0xF>(pr);   // row_shr:2
        pr *= dpp_mov1<0x114, 0xF>(pr);   // row_shr:4
        pr *= dpp_mov1<0x118, 0xF>(pr);   // row_shr:8
        pr *= dpp_mov1<0x142, 0xA>(pr);   // row_bcast:15
        pr *= dpp_mov1<0x143, 0xC>(pr);   // row_bcast:31
        const float x = t * pr;           // sigmoid(vh) * exclusive-prod
        Ahi[row * ASTR + mod * RR + lane] = f2bf(x);
    }
    __syncthreads();

    // ---- MFMA K-loop: A from LDS, B from global (L2-hot) ----
    floatx4 acc[MI][4];
    #pragma unroll
    for (int mi = 0; mi < MI; ++mi)
        #pragma unroll
        for (int ni = 0; ni < 4; ++ni)
            acc[mi][ni] = (floatx4){0.f, 0.f, 0.f, 0.f};

    #pragma unroll
    for (int ch = 0; ch < NCH; ++ch) {
        short8 ah[MI];
        const int ka = ch * 32 + lg * 8;
        #pragma unroll
        for (int mi = 0; mi < MI; ++mi)
            ah[mi] = *reinterpret_cast<const short8*>(&Ahi[(mi * 16 + l15) * ASTR + ka]);
        #pragma unroll
        for (int ni = 0; ni < 4; ++ni) {
            const int off = ((ch * 4 + lg) * 512 + wcol0 + ni * 16 + l15) * 8;
            const short8 bh = *reinterpret_cast<const short8*>(&Bhi[off]);
            const short8 bl = *reinterpret_cast<const short8*>(&Blo[off]);
            #pragma unroll
            for (int mi = 0; mi < MI; ++mi) {
                acc[mi][ni] = __builtin_amdgcn_mfma_f32_16x16x32_bf16(ah[mi], bh, acc[mi][ni], 0, 0, 0);
                acc[mi][ni] = __builtin_amdgcn_mfma_f32_16x16x32_bf16(ah[mi], bl, acc[mi][ni], 0, 0, 0);
            }
        }
    }

    // ---- epilogue: +b', hw sincos (revolutions), dot w_mu, reduce ----
    float rp[MI][4];
    #pragma unroll
    for (int mi = 0; mi < MI; ++mi)
        #pragma unroll
        for (int r = 0; r < 4; ++r) rp[mi][r] = 0.f;

    #pragma unroll
    for (int ni = 0; ni < 4; ++ni) {
        const int c = wcol0 + ni * 16 + l15;
        const float bb = bvec[c] * INV2PI;
        const float w1 = w_mu[c];
        const float w2 = w_mu[MM + c];
        #pragma unroll
        for (int mi = 0; mi < MI; ++mi)
            #pragma unroll
            for (int r = 0; r < 4; ++r) {
                const float psi = acc[mi][ni][r] + bb;      // revolutions
                const float sn = __builtin_amdgcn_sinf(psi);
                const float cs = __builtin_amdgcn_cosf(psi);
                rp[mi][r] = fmaf(cs, w1, fmaf(sn, w2, rp[mi][r]));
            }
    }

    #pragma unroll
    for (int mi = 0; mi < MI; ++mi)
        #pragma unroll
        for (int r = 0; r < 4; ++r) {
            const float v = red16(rp[mi][r]);
            if (l15 == 0) red[wid][mi * 16 + lg * 4 + r] = v;
        }
    __syncthreads();

    if (tid < ROWS) {
        float s = 0.f;
        #pragma unroll
        for (int w = 0; w < 8; ++w) s += red[w][tid];
        out[rowBase + tid] = 1.f / (1.f + expf(-s));
    }
}

extern "C" void kernel_launch(void* const* d_in, const int* in_sizes, int n_in,
                              void* d_out, int out_size, void* d_ws, size_t ws_size,
                              hipStream_t stream) {
    const int*   indices = (const int*)d_in[0];
    const float* v0 = (const float*)d_in[1];
    const float* v1 = (const float*)d_in[2];
    const float* v2 = (const float*)d_in[3];
    const float* v3 = (const float*)d_in[4];
    const float* S  = (const float*)d_in[5];
    const float* bb = (const float*)d_in[6];
    const float* w  = (const float*)d_in[7];
    float* out = (float*)d_out;

    ushort* Bhi = (ushort*)d_ws;               // 512*256 bf16 = 256 KB
    ushort* Blo = Bhi + MM * KK;               // 256 KB

    hipLaunchKernelGGL(conv_S, dim3(MM * KK / (256 * 8)), dim3(256), 0, stream,
                       S, Bhi, Blo);
    hipLaunchKernelGGL(nest2_mfma, dim3(B_TOTAL / ROWS), dim3(512), 0, stream,
                       indices, v0, v1, v2, v3, Bhi, Blo, bb, w, out);
}

// Round 8
// 23.049 us; speedup vs baseline: 1.4905x; 1.3921x over previous
//
#include <hip/hip_runtime.h>
#include <math.h>

#define B_TOTAL 16384
#define RR 64
#define KK 256          // 4*R
#define MM 512
#define ROWS 16         // batch rows per block
#define NCH 8           // K chunks of 32
#define NNI 8           // 16-col tiles per wave (128 cols/wave, 4 waves)
#define ASTR 264        // A LDS row stride (fp16 elems)
#define INV2PI 0.15915494309189535f

typedef __attribute__((ext_vector_type(8))) _Float16 half8;
typedef __attribute__((ext_vector_type(4))) float floatx4;

// DPP mov with multiplicative identity for invalid/unwritten lanes
template<int CTRL, int RMASK>
static __device__ inline float dpp_mov1(float src) {
    int s = __builtin_bit_cast(int, src);
    int o = __builtin_bit_cast(int, 1.0f);
    int r = __builtin_amdgcn_update_dpp(o, s, CTRL, RMASK, 0xF, false);
    return __builtin_bit_cast(float, r);
}
template<int CTRL>
static __device__ inline float dpp_swap(float src) {
    int s = __builtin_bit_cast(int, src);
    int r = __builtin_amdgcn_update_dpp(s, s, CTRL, 0xF, 0xF, false);
    return __builtin_bit_cast(float, r);
}
static __device__ inline float red16(float x) {
    x += dpp_swap<0xB1>(x);    // quad_perm xor1
    x += dpp_swap<0x4E>(x);    // quad_perm xor2
    x += dpp_swap<0x141>(x);   // row_half_mirror
    x += dpp_swap<0x140>(x);   // row_mirror
    return x;
}

// ---- kernel 1: S -> fp16 of S/(2*pi), MFMA B-fragment order ----
// Bh[(o*512 + c)*8 + j] = S[c][o*8+j] / 2pi
__global__ __launch_bounds__(256)
void conv_S(const float* __restrict__ S, _Float16* __restrict__ Bh)
{
    const int F = blockIdx.x * 256 + threadIdx.x;   // F = o*512 + c
    const int o = F >> 9;
    const int c = F & 511;
    const float* src = &S[c * KK + o * 8];
    float v[8];
    *reinterpret_cast<float4*>(&v[0]) = *reinterpret_cast<const float4*>(src);
    *reinterpret_cast<float4*>(&v[4]) = *reinterpret_cast<const float4*>(src + 4);
    half8 hv;
    #pragma unroll
    for (int j = 0; j < 8; ++j)
        hv[j] = (_Float16)(v[j] * INV2PI);
    *reinterpret_cast<half8*>(&Bh[F * 8]) = hv;
}

// ---- kernel 2: gather + stick-break + fp16 MFMA + sincos + reduce ----
__global__ __launch_bounds__(256, 6)
void nest2_mfma(const int* __restrict__ indices,
                const float* __restrict__ v0, const float* __restrict__ v1,
                const float* __restrict__ v2, const float* __restrict__ v3,
                const _Float16* __restrict__ Bh,
                const float* __restrict__ bvec, const float* __restrict__ w_mu,
                float* __restrict__ out)
{
    __shared__ alignas(16) _Float16 Ah[ROWS * ASTR];
    __shared__ float red[4][ROWS];

    const int tid = threadIdx.x;
    const int rowBase = blockIdx.x * ROWS;
    const int wid  = __builtin_amdgcn_readfirstlane(tid >> 6);   // 0..3
    const int lane = tid & 63;
    const int l15  = lane & 15;
    const int lg   = lane >> 4;
    const int wcol0 = wid * 128;   // this wave's 128-col slice

    // ---- gather loads (wave-uniform row addresses -> coalesced) ----
    const int* ip = indices + rowBase * 4 + wid * 16;
    const float* vts[4] = {v0, v1, v2, v3};
    float vh[16];
    #pragma unroll
    for (int it = 0; it < 16; ++it) {
        const int mod = it & 3;            // wid*16 ≡ 0 (mod 4)
        vh[it] = vts[mod][ip[it] * RR + lane];
    }

    // ---- stick-breaking via DPP product-scan -> Ah (fp16) ----
    #pragma unroll
    for (int it = 0; it < 16; ++it) {
        const int p   = wid * 16 + it;     // 64 (row,mod) pairs per block
        const int row = p >> 2;
        const int mod = p & 3;
        const float t  = __expf(vh[it]);                    // e^{vh}
        const float um = __builtin_amdgcn_rcpf(1.f + t);    // sigmoid(-vh)
        float pr = um;                                      // inclusive scan
        pr *= dpp_mov1<0x111, 0xF>(pr);   // row_shr:1
        pr *= dpp_mov1<0x112, 0xF>(pr);   // row_shr:2
        pr *= dpp_mov1<0x114, 0xF>(pr);   // row_shr:4
        pr *= dpp_mov1<0x118, 0xF>(pr);   // row_shr:8
        pr *= dpp_mov1<0x142, 0xA>(pr);   // row_bcast:15
        pr *= dpp_mov1<0x143, 0xC>(pr);   // row_bcast:31
        const float x = t * pr;           // sigmoid(vh) * exclusive-prod
        Ah[row * ASTR + mod * RR + lane] = (_Float16)x;
    }
    __syncthreads();

    // ---- fp16 MFMA K-loop: A from LDS, B from global (L2-hot) ----
    floatx4 acc[NNI];
    #pragma unroll
    for (int ni = 0; ni < NNI; ++ni)
        acc[ni] = (floatx4){0.f, 0.f, 0.f, 0.f};

    #pragma unroll
    for (int ch = 0; ch < NCH; ++ch) {
        const half8 ah = *reinterpret_cast<const half8*>(&Ah[l15 * ASTR + ch * 32 + lg * 8]);
        #pragma unroll
        for (int ni = 0; ni < NNI; ++ni) {
            const int off = ((ch * 4 + lg) * 512 + wcol0 + ni * 16 + l15) * 8;
            const half8 bh = *reinterpret_cast<const half8*>(&Bh[off]);
            acc[ni] = __builtin_amdgcn_mfma_f32_16x16x32_f16(ah, bh, acc[ni], 0, 0, 0);
        }
    }

    // ---- epilogue: +b', hw sincos (revolutions), dot w_mu, reduce ----
    float rp[4] = {0.f, 0.f, 0.f, 0.f};
    #pragma unroll
    for (int ni = 0; ni < NNI; ++ni) {
        const int c = wcol0 + ni * 16 + l15;
        const float bb = bvec[c] * INV2PI;
        const float w1 = w_mu[c];
        const float w2 = w_mu[MM + c];
        #pragma unroll
        for (int r = 0; r < 4; ++r) {
            const float psi = acc[ni][r] + bb;          // revolutions
            const float sn = __builtin_amdgcn_sinf(psi);
            const float cs = __builtin_amdgcn_cosf(psi);
            rp[r] = fmaf(cs, w1, fmaf(sn, w2, rp[r]));
        }
    }

    #pragma unroll
    for (int r = 0; r < 4; ++r) {
        const float v = red16(rp[r]);                   // sum over 16 cols
        if (l15 == 0) red[wid][lg * 4 + r] = v;         // row = lg*4 + r
    }
    __syncthreads();

    if (tid < ROWS) {
        const float s = red[0][tid] + red[1][tid] + red[2][tid] + red[3][tid];
        out[rowBase + tid] = 1.f / (1.f + expf(-s));
    }
}

extern "C" void kernel_launch(void* const* d_in, const int* in_sizes, int n_in,
                              void* d_out, int out_size, void* d_ws, size_t ws_size,
                              hipStream_t stream) {
    const int*   indices = (const int*)d_in[0];
    const float* v0 = (const float*)d_in[1];
    const float* v1 = (const float*)d_in[2];
    const float* v2 = (const float*)d_in[3];
    const float* v3 = (const float*)d_in[4];
    const float* S  = (const float*)d_in[5];
    const float* bb = (const float*)d_in[6];
    const float* w  = (const float*)d_in[7];
    float* out = (float*)d_out;

    _Float16* Bh = (_Float16*)d_ws;            // 512*256 fp16 = 256 KB

    hipLaunchKernelGGL(conv_S, dim3(MM * KK / (256 * 8)), dim3(256), 0, stream,
                       S, Bh);
    hipLaunchKernelGGL(nest2_mfma, dim3(B_TOTAL / ROWS), dim3(256), 0, stream,
                       indices, v0, v1, v2, v3, Bh, bb, w, out);
}

// Round 9
// 22.110 us; speedup vs baseline: 1.5538x; 1.0425x over previous
//
#include <hip/hip_runtime.h>
#include <math.h>

#define B_TOTAL 16384
#define RR 64
#define KK 256          // 4*R
#define MM 512
#define ROWS 16         // batch rows per block
#define NCH 8           // K chunks of 32
#define NNI 8           // 16-col tiles per wave (128 cols/wave, 4 waves)
#define ASTR 264        // A LDS row stride (fp16 elems)
#define INV2PI 0.15915494309189535f

typedef __attribute__((ext_vector_type(8))) _Float16 half8;
typedef __attribute__((ext_vector_type(4))) float floatx4;

// DPP mov with multiplicative identity for invalid/unwritten lanes
template<int CTRL, int RMASK>
static __device__ inline float dpp_mov1(float src) {
    int s = __builtin_bit_cast(int, src);
    int o = __builtin_bit_cast(int, 1.0f);
    int r = __builtin_amdgcn_update_dpp(o, s, CTRL, RMASK, 0xF, false);
    return __builtin_bit_cast(float, r);
}
template<int CTRL>
static __device__ inline float dpp_swap(float src) {
    int s = __builtin_bit_cast(int, src);
    int r = __builtin_amdgcn_update_dpp(s, s, CTRL, 0xF, 0xF, false);
    return __builtin_bit_cast(float, r);
}
static __device__ inline float red16(float x) {
    x += dpp_swap<0xB1>(x);    // quad_perm xor1
    x += dpp_swap<0x4E>(x);    // quad_perm xor2
    x += dpp_swap<0x141>(x);   // row_half_mirror
    x += dpp_swap<0x140>(x);   // row_mirror
    return x;
}

// ---- kernel 1: S -> fp16 of S/(2*pi), MFMA B-fragment order ----
__global__ __launch_bounds__(256)
void conv_S(const float* __restrict__ S, _Float16* __restrict__ Bh)
{
    const int F = blockIdx.x * 256 + threadIdx.x;   // F = o*512 + c
    const int o = F >> 9;
    const int c = F & 511;
    const float* src = &S[c * KK + o * 8];
    float v[8];
    *reinterpret_cast<float4*>(&v[0]) = *reinterpret_cast<const float4*>(src);
    *reinterpret_cast<float4*>(&v[4]) = *reinterpret_cast<const float4*>(src + 4);
    half8 hv;
    #pragma unroll
    for (int j = 0; j < 8; ++j)
        hv[j] = (_Float16)(v[j] * INV2PI);
    *reinterpret_cast<half8*>(&Bh[F * 8]) = hv;
}

// ---- kernel 2: gather + stick-break + fp16 MFMA + sincos + reduce ----
__global__ __launch_bounds__(256, 4)
void nest2_mfma(const int* __restrict__ indices,
                const float* __restrict__ v0, const float* __restrict__ v1,
                const float* __restrict__ v2, const float* __restrict__ v3,
                const _Float16* __restrict__ Bh,
                const float* __restrict__ bvec, const float* __restrict__ w_mu,
                float* __restrict__ out)
{
    __shared__ alignas(16) _Float16 Ah[ROWS * ASTR];
    __shared__ float red[4][ROWS];

    const int tid = threadIdx.x;
    const int rowBase = blockIdx.x * ROWS;
    const int wid  = __builtin_amdgcn_readfirstlane(tid >> 6);   // 0..3
    const int lane = tid & 63;
    const int l15  = lane & 15;
    const int lg   = lane >> 4;
    const int wcol0 = wid * 128;   // this wave's 128-col slice

    // B fragment byte-offset helper (compile-time ch, ni after unroll)
    #define BOFF(ch, ni) ((((ch) * 4 + lg) * 512 + wcol0 + (ni) * 16 + l15) * 8)

    // ---- gather loads (wave-uniform row addresses -> coalesced) ----
    const int* ip = indices + rowBase * 4 + wid * 16;
    const float* vts[4] = {v0, v1, v2, v3};
    float vh[16];
    #pragma unroll
    for (int it = 0; it < 16; ++it) {
        const int mod = it & 3;            // wid*16 ≡ 0 (mod 4)
        vh[it] = vts[mod][ip[it] * RR + lane];
    }

    // ---- prefetch ch-0 B fragments (independent of scan/LDS) ----
    half8 b[NNI];
    #pragma unroll
    for (int ni = 0; ni < NNI; ++ni)
        b[ni] = *reinterpret_cast<const half8*>(&Bh[BOFF(0, ni)]);

    // ---- stick-breaking via DPP product-scan -> Ah (fp16) ----
    #pragma unroll
    for (int it = 0; it < 16; ++it) {
        const int p   = wid * 16 + it;     // 64 (row,mod) pairs per block
        const int row = p >> 2;
        const int mod = p & 3;
        const float t  = __expf(vh[it]);                    // e^{vh}
        const float um = __builtin_amdgcn_rcpf(1.f + t);    // sigmoid(-vh)
        float pr = um;                                      // inclusive scan
        pr *= dpp_mov1<0x111, 0xF>(pr);   // row_shr:1
        pr *= dpp_mov1<0x112, 0xF>(pr);   // row_shr:2
        pr *= dpp_mov1<0x114, 0xF>(pr);   // row_shr:4
        pr *= dpp_mov1<0x118, 0xF>(pr);   // row_shr:8
        pr *= dpp_mov1<0x142, 0xA>(pr);   // row_bcast:15
        pr *= dpp_mov1<0x143, 0xC>(pr);   // row_bcast:31
        const float x = t * pr;           // sigmoid(vh) * exclusive-prod
        Ah[row * ASTR + mod * RR + lane] = (_Float16)x;
    }
    __syncthreads();

    // ---- fp16 MFMA K-loop, register-double-buffered B ----
    floatx4 acc[NNI];
    #pragma unroll
    for (int ni = 0; ni < NNI; ++ni)
        acc[ni] = (floatx4){0.f, 0.f, 0.f, 0.f};

    #pragma unroll
    for (int ch = 0; ch < NCH; ++ch) {
        const half8 ah = *reinterpret_cast<const half8*>(
            &Ah[l15 * ASTR + ch * 32 + lg * 8]);
        half8 bn[NNI];
        if (ch + 1 < NCH) {
            #pragma unroll
            for (int ni = 0; ni < NNI; ++ni)
                bn[ni] = *reinterpret_cast<const half8*>(&Bh[BOFF(ch + 1, ni)]);
        }
        __builtin_amdgcn_s_setprio(1);
        #pragma unroll
        for (int ni = 0; ni < NNI; ++ni)
            acc[ni] = __builtin_amdgcn_mfma_f32_16x16x32_f16(ah, b[ni], acc[ni], 0, 0, 0);
        __builtin_amdgcn_s_setprio(0);
        if (ch + 1 < NCH) {
            #pragma unroll
            for (int ni = 0; ni < NNI; ++ni)
                b[ni] = bn[ni];
        }
    }

    // ---- epilogue: +b', hw sincos (revolutions), dot w_mu, reduce ----
    float rp[4] = {0.f, 0.f, 0.f, 0.f};
    #pragma unroll
    for (int ni = 0; ni < NNI; ++ni) {
        const int c = wcol0 + ni * 16 + l15;
        const float bb = bvec[c] * INV2PI;
        const float w1 = w_mu[c];
        const float w2 = w_mu[MM + c];
        #pragma unroll
        for (int r = 0; r < 4; ++r) {
            const float psi = acc[ni][r] + bb;          // revolutions
            const float sn = __builtin_amdgcn_sinf(psi);
            const float cs = __builtin_amdgcn_cosf(psi);
            rp[r] = fmaf(cs, w1, fmaf(sn, w2, rp[r]));
        }
    }

    #pragma unroll
    for (int r = 0; r < 4; ++r) {
        const float v = red16(rp[r]);                   // sum over 16 cols
        if (l15 == 0) red[wid][lg * 4 + r] = v;         // row = lg*4 + r
    }
    __syncthreads();

    if (tid < ROWS) {
        const float s = red[0][tid] + red[1][tid] + red[2][tid] + red[3][tid];
        out[rowBase + tid] = 1.f / (1.f + expf(-s));
    }
    #undef BOFF
}

extern "C" void kernel_launch(void* const* d_in, const int* in_sizes, int n_in,
                              void* d_out, int out_size, void* d_ws, size_t ws_size,
                              hipStream_t stream) {
    const int*   indices = (const int*)d_in[0];
    const float* v0 = (const float*)d_in[1];
    const float* v1 = (const float*)d_in[2];
    const float* v2 = (const float*)d_in[3];
    const float* v3 = (const float*)d_in[4];
    const float* S  = (const float*)d_in[5];
    const float* bb = (const float*)d_in[6];
    const float* w  = (const float*)d_in[7];
    float* out = (float*)d_out;

    _Float16* Bh = (_Float16*)d_ws;            // 512*256 fp16 = 256 KB

    hipLaunchKernelGGL(conv_S, dim3(MM * KK / (256 * 8)), dim3(256), 0, stream,
                       S, Bh);
    hipLaunchKernelGGL(nest2_mfma, dim3(B_TOTAL / ROWS), dim3(256), 0, stream,
                       indices, v0, v1, v2, v3, Bh, bb, w, out);
}

// Round 10
// 18.937 us; speedup vs baseline: 1.8141x; 1.1675x over previous
//
#include <hip/hip_runtime.h>
#include <math.h>

#define B_TOTAL 16384
#define RR 64
#define KK 256          // 4*R
#define MM 512
#define ROWS 32         // batch rows per block
#define NCH 8           // K chunks of 32
#define NNI 4           // 16-col tiles per wave (64 cols/wave, 8 waves)
#define MI 2            // 16-row M-tiles per wave
#define ASTR 264        // A LDS row stride (fp16 elems)
#define INV2PI 0.15915494309189535f

typedef __attribute__((ext_vector_type(8))) _Float16 half8;
typedef __attribute__((ext_vector_type(4))) float floatx4;

// DPP mov with multiplicative identity for invalid/unwritten lanes
template<int CTRL, int RMASK>
static __device__ inline float dpp_mov1(float src) {
    int s = __builtin_bit_cast(int, src);
    int o = __builtin_bit_cast(int, 1.0f);
    int r = __builtin_amdgcn_update_dpp(o, s, CTRL, RMASK, 0xF, false);
    return __builtin_bit_cast(float, r);
}
template<int CTRL>
static __device__ inline float dpp_swap(float src) {
    int s = __builtin_bit_cast(int, src);
    int r = __builtin_amdgcn_update_dpp(s, s, CTRL, 0xF, 0xF, false);
    return __builtin_bit_cast(float, r);
}
static __device__ inline float red16(float x) {
    x += dpp_swap<0xB1>(x);    // quad_perm xor1
    x += dpp_swap<0x4E>(x);    // quad_perm xor2
    x += dpp_swap<0x141>(x);   // row_half_mirror
    x += dpp_swap<0x140>(x);   // row_mirror
    return x;
}

// ---- kernel 1: S -> fp16 of S/(2*pi), MFMA B-fragment order ----
__global__ __launch_bounds__(256)
void conv_S(const float* __restrict__ S, _Float16* __restrict__ Bh)
{
    const int F = blockIdx.x * 256 + threadIdx.x;   // F = o*512 + c
    const int o = F >> 9;
    const int c = F & 511;
    const float* src = &S[c * KK + o * 8];
    float v[8];
    *reinterpret_cast<float4*>(&v[0]) = *reinterpret_cast<const float4*>(src);
    *reinterpret_cast<float4*>(&v[4]) = *reinterpret_cast<const float4*>(src + 4);
    half8 hv;
    #pragma unroll
    for (int j = 0; j < 8; ++j)
        hv[j] = (_Float16)(v[j] * INV2PI);
    *reinterpret_cast<half8*>(&Bh[F * 8]) = hv;
}

// ---- kernel 2: gather + stick-break + fp16 MFMA + sincos + reduce ----
__global__ __launch_bounds__(512, 4)
void nest2_mfma(const int* __restrict__ indices,
                const float* __restrict__ v0, const float* __restrict__ v1,
                const float* __restrict__ v2, const float* __restrict__ v3,
                const _Float16* __restrict__ Bh,
                const float* __restrict__ bvec, const float* __restrict__ w_mu,
                float* __restrict__ out)
{
    __shared__ alignas(16) _Float16 Ah[ROWS * ASTR];
    __shared__ float red[8][ROWS];

    const int tid = threadIdx.x;
    const int rowBase = blockIdx.x * ROWS;
    const int wid  = __builtin_amdgcn_readfirstlane(tid >> 6);   // 0..7
    const int lane = tid & 63;
    const int l15  = lane & 15;
    const int lg   = lane >> 4;
    const int wcol0 = wid * 64;    // this wave's 64-col slice

    #define BOFF(ch, ni) ((((ch) * 4 + lg) * 512 + wcol0 + (ni) * 16 + l15) * 8)

    // ---- gather loads (wave-uniform row addresses -> coalesced) ----
    const int* ip = indices + rowBase * 4 + wid * 16;
    const float* vts[4] = {v0, v1, v2, v3};
    float vh[16];
    #pragma unroll
    for (int it = 0; it < 16; ++it) {
        const int mod = it & 3;            // wid*16 ≡ 0 (mod 4)
        vh[it] = vts[mod][ip[it] * RR + lane];
    }

    // ---- prefetch ch-0 B fragments + epilogue constants ----
    half8 b[NNI];
    #pragma unroll
    for (int ni = 0; ni < NNI; ++ni)
        b[ni] = *reinterpret_cast<const half8*>(&Bh[BOFF(0, ni)]);
    float bbv[NNI], w1v[NNI], w2v[NNI];
    #pragma unroll
    for (int ni = 0; ni < NNI; ++ni) {
        const int c = wcol0 + ni * 16 + l15;
        bbv[ni] = bvec[c] * INV2PI;
        w1v[ni] = w_mu[c];
        w2v[ni] = w_mu[MM + c];
    }

    // ---- stick-breaking via DPP product-scan -> Ah (fp16) ----
    #pragma unroll
    for (int it = 0; it < 16; ++it) {
        const int p   = wid * 16 + it;     // 128 (row,mod) pairs per block
        const int row = p >> 2;
        const int mod = p & 3;
        const float t  = __expf(vh[it]);                    // e^{vh}
        const float um = __builtin_amdgcn_rcpf(1.f + t);    // sigmoid(-vh)
        float pr = um;                                      // inclusive scan
        pr *= dpp_mov1<0x111, 0xF>(pr);   // row_shr:1
        pr *= dpp_mov1<0x112, 0xF>(pr);   // row_shr:2
        pr *= dpp_mov1<0x114, 0xF>(pr);   // row_shr:4
        pr *= dpp_mov1<0x118, 0xF>(pr);   // row_shr:8
        pr *= dpp_mov1<0x142, 0xA>(pr);   // row_bcast:15
        pr *= dpp_mov1<0x143, 0xC>(pr);   // row_bcast:31
        const float x = t * pr;           // sigmoid(vh) * exclusive-prod
        Ah[row * ASTR + mod * RR + lane] = (_Float16)x;
    }
    __syncthreads();

    // ---- fp16 MFMA K-loop, register-double-buffered B ----
    floatx4 acc[MI][NNI];
    #pragma unroll
    for (int mi = 0; mi < MI; ++mi)
        #pragma unroll
        for (int ni = 0; ni < NNI; ++ni)
            acc[mi][ni] = (floatx4){0.f, 0.f, 0.f, 0.f};

    #pragma unroll
    for (int ch = 0; ch < NCH; ++ch) {
        half8 ah[MI];
        #pragma unroll
        for (int mi = 0; mi < MI; ++mi)
            ah[mi] = *reinterpret_cast<const half8*>(
                &Ah[(mi * 16 + l15) * ASTR + ch * 32 + lg * 8]);
        half8 bn[NNI];
        if (ch + 1 < NCH) {
            #pragma unroll
            for (int ni = 0; ni < NNI; ++ni)
                bn[ni] = *reinterpret_cast<const half8*>(&Bh[BOFF(ch + 1, ni)]);
        }
        __builtin_amdgcn_s_setprio(1);
        #pragma unroll
        for (int ni = 0; ni < NNI; ++ni)
            #pragma unroll
            for (int mi = 0; mi < MI; ++mi)
                acc[mi][ni] = __builtin_amdgcn_mfma_f32_16x16x32_f16(ah[mi], b[ni], acc[mi][ni], 0, 0, 0);
        __builtin_amdgcn_s_setprio(0);
        if (ch + 1 < NCH) {
            #pragma unroll
            for (int ni = 0; ni < NNI; ++ni)
                b[ni] = bn[ni];
        }
    }

    // ---- epilogue: +b', hw sincos (revolutions), dot w_mu, reduce ----
    float rp[MI][4];
    #pragma unroll
    for (int mi = 0; mi < MI; ++mi)
        #pragma unroll
        for (int r = 0; r < 4; ++r) rp[mi][r] = 0.f;

    #pragma unroll
    for (int ni = 0; ni < NNI; ++ni) {
        #pragma unroll
        for (int mi = 0; mi < MI; ++mi)
            #pragma unroll
            for (int r = 0; r < 4; ++r) {
                const float psi = acc[mi][ni][r] + bbv[ni];   // revolutions
                const float sn = __builtin_amdgcn_sinf(psi);
                const float cs = __builtin_amdgcn_cosf(psi);
                rp[mi][r] = fmaf(cs, w1v[ni], fmaf(sn, w2v[ni], rp[mi][r]));
            }
    }

    #pragma unroll
    for (int mi = 0; mi < MI; ++mi)
        #pragma unroll
        for (int r = 0; r < 4; ++r) {
            const float v = red16(rp[mi][r]);                 // sum over 16 cols
            if (l15 == 0) red[wid][mi * 16 + lg * 4 + r] = v;
        }
    __syncthreads();

    if (tid < ROWS) {
        float s = 0.f;
        #pragma unroll
        for (int w = 0; w < 8; ++w) s += red[w][tid];
        out[rowBase + tid] = 1.f / (1.f + expf(-s));
    }
    #undef BOFF
}

extern "C" void kernel_launch(void* const* d_in, const int* in_sizes, int n_in,
                              void* d_out, int out_size, void* d_ws, size_t ws_size,
                              hipStream_t stream) {
    const int*   indices = (const int*)d_in[0];
    const float* v0 = (const float*)d_in[1];
    const float* v1 = (const float*)d_in[2];
    const float* v2 = (const float*)d_in[3];
    const float* v3 = (const float*)d_in[4];
    const float* S  = (const float*)d_in[5];
    const float* bb = (const float*)d_in[6];
    const float* w  = (const float*)d_in[7];
    float* out = (float*)d_out;

    _Float16* Bh = (_Float16*)d_ws;            // 512*256 fp16 = 256 KB

    hipLaunchKernelGGL(conv_S, dim3(MM * KK / (256 * 8)), dim3(256), 0, stream,
                       S, Bh);
    hipLaunchKernelGGL(nest2_mfma, dim3(B_TOTAL / ROWS), dim3(512), 0, stream,
                       indices, v0, v1, v2, v3, Bh, bb, w, out);
}